// Round 1
// baseline (7043.040 us; speedup 1.0000x reference)
//
#include <hip/hip_runtime.h>
#include <math.h>

#define B_  32
#define LT_ 512
#define LI_ 576
#define D_  768
#define H_  8
#define K_  512

#define TBM 64
#define TBN 64
#define TBK 16

// MODE 0 (NT): C[m,n] = sum_k A[m*lda+k] * B[n*ldb+k]
// MODE 1 (TN): C[m,n] = sum_k A[k*lda+m] * B[k*ldb+n]
// MODE 2 (NN): C[m,n] = sum_k A[m*lda+k] * B[k*ldb+n]
// All dims here are multiples of 64 (M,N) and 16 (Kd); strides multiple of 4 floats.
template<int MODE>
__global__ __launch_bounds__(256) void gemm_kern(
    const float* __restrict__ Ag, const float* __restrict__ Bg, float* __restrict__ Cg,
    int Kd, int lda, int ldb, int ldc,
    long sA, long sB, long sC)
{
  const float* A  = Ag + (long)blockIdx.z * sA;
  const float* Bm = Bg + (long)blockIdx.z * sB;
  float*       C  = Cg + (long)blockIdx.z * sC;
  __shared__ float As[TBK][TBM];
  __shared__ float Bs[TBK][TBN];
  const int t  = threadIdx.x;
  const int tx = t & 15, ty = t >> 4;
  const int m0 = blockIdx.x * TBM, n0 = blockIdx.y * TBN;
  const int rrow = t >> 2,  rkq = (t & 3) << 2;   // transposing-load mapping (64 rows x 16 k)
  const int kr   = t >> 4,  cq  = (t & 15) << 2;  // direct-load mapping (16 k-rows x 64 cols)
  float acc[4][4] = {};
  for (int k0 = 0; k0 < Kd; k0 += TBK) {
    float4 av, bv;
    if (MODE == 0 || MODE == 2) av = *(const float4*)(A  + (long)(m0 + rrow) * lda + (k0 + rkq));
    else                        av = *(const float4*)(A  + (long)(k0 + kr)   * lda + (m0 + cq));
    if (MODE == 0)              bv = *(const float4*)(Bm + (long)(n0 + rrow) * ldb + (k0 + rkq));
    else                        bv = *(const float4*)(Bm + (long)(k0 + kr)   * ldb + (n0 + cq));
    __syncthreads();
    if (MODE == 0 || MODE == 2) {
      As[rkq+0][rrow] = av.x; As[rkq+1][rrow] = av.y; As[rkq+2][rrow] = av.z; As[rkq+3][rrow] = av.w;
    } else {
      *(float4*)&As[kr][cq] = av;
    }
    if (MODE == 0) {
      Bs[rkq+0][rrow] = bv.x; Bs[rkq+1][rrow] = bv.y; Bs[rkq+2][rrow] = bv.z; Bs[rkq+3][rrow] = bv.w;
    } else {
      *(float4*)&Bs[kr][cq] = bv;
    }
    __syncthreads();
    #pragma unroll
    for (int kk = 0; kk < TBK; ++kk) {
      const float4 a = *(const float4*)&As[kk][ty << 2];
      const float4 b = *(const float4*)&Bs[kk][tx << 2];
      acc[0][0] = fmaf(a.x, b.x, acc[0][0]);
      acc[0][1] = fmaf(a.x, b.y, acc[0][1]);
      acc[0][2] = fmaf(a.x, b.z, acc[0][2]);
      acc[0][3] = fmaf(a.x, b.w, acc[0][3]);
      acc[1][0] = fmaf(a.y, b.x, acc[1][0]);
      acc[1][1] = fmaf(a.y, b.y, acc[1][1]);
      acc[1][2] = fmaf(a.y, b.z, acc[1][2]);
      acc[1][3] = fmaf(a.y, b.w, acc[1][3]);
      acc[2][0] = fmaf(a.z, b.x, acc[2][0]);
      acc[2][1] = fmaf(a.z, b.y, acc[2][1]);
      acc[2][2] = fmaf(a.z, b.z, acc[2][2]);
      acc[2][3] = fmaf(a.z, b.w, acc[2][3]);
      acc[3][0] = fmaf(a.w, b.x, acc[3][0]);
      acc[3][1] = fmaf(a.w, b.y, acc[3][1]);
      acc[3][2] = fmaf(a.w, b.z, acc[3][2]);
      acc[3][3] = fmaf(a.w, b.w, acc[3][3]);
    }
  }
  #pragma unroll
  for (int i = 0; i < 4; ++i) {
    float4 v = make_float4(acc[i][0], acc[i][1], acc[i][2], acc[i][3]);
    *(float4*)(C + (long)(m0 + (ty << 2) + i) * ldc + (n0 + (tx << 2))) = v;
  }
}

// out[r] = sum_k tanh(base[r*Kd+k] + add[r*Kd+k]) * w[k]
__global__ __launch_bounds__(256) void tanh_dot(
    const float* __restrict__ base, const float* __restrict__ add,
    const float* __restrict__ w, float* __restrict__ out, int Kd)
{
  const long r = blockIdx.x;
  const int  t = threadIdx.x;
  const float* bp = base + r * Kd;
  const float* ap = add  + r * Kd;
  float s = 0.f;
  for (int k = t; k < Kd; k += 256)
    s = fmaf(tanhf(bp[k] + ap[k]), w[k], s);
  #pragma unroll
  for (int o = 32; o > 0; o >>= 1) s += __shfl_down(s, o, 64);
  __shared__ float red[4];
  if ((t & 63) == 0) red[t >> 6] = s;
  __syncthreads();
  if (t == 0) out[r] = red[0] + red[1] + red[2] + red[3];
}

// per (b,h): softmax(lv) over LI, softmax(lq) over LT, then
// head[h,b,d] = sum_y attv[y]*image[b,y,d] + sum_x attq[x]*text[b,x,d]
__global__ __launch_bounds__(256) void softmax_ctx(
    const float* __restrict__ lv, const float* __restrict__ lq,
    const float* __restrict__ image, const float* __restrict__ text,
    float* __restrict__ head)
{
  const int b = blockIdx.x, h = blockIdx.y;
  const int t = threadIdx.x;
  __shared__ float attv[LI_];
  __shared__ float attq[LT_];
  __shared__ float red[4];

  // ---- softmax over image tokens ----
  const float* lvp = lv + ((long)h * B_ + b) * LI_;
  float m = -1e30f;
  for (int i = t; i < LI_; i += 256) m = fmaxf(m, lvp[i]);
  #pragma unroll
  for (int o = 32; o > 0; o >>= 1) m = fmaxf(m, __shfl_down(m, o, 64));
  if ((t & 63) == 0) red[t >> 6] = m;
  __syncthreads();
  m = fmaxf(fmaxf(red[0], red[1]), fmaxf(red[2], red[3]));
  __syncthreads();
  float s = 0.f;
  for (int i = t; i < LI_; i += 256) { float e = __expf(lvp[i] - m); attv[i] = e; s += e; }
  #pragma unroll
  for (int o = 32; o > 0; o >>= 1) s += __shfl_down(s, o, 64);
  if ((t & 63) == 0) red[t >> 6] = s;
  __syncthreads();
  s = red[0] + red[1] + red[2] + red[3];
  {
    float inv = 1.f / s;
    for (int i = t; i < LI_; i += 256) attv[i] *= inv;
  }
  __syncthreads();

  // ---- softmax over text tokens ----
  const float* lqp = lq + ((long)h * B_ + b) * LT_;
  m = -1e30f;
  for (int i = t; i < LT_; i += 256) m = fmaxf(m, lqp[i]);
  #pragma unroll
  for (int o = 32; o > 0; o >>= 1) m = fmaxf(m, __shfl_down(m, o, 64));
  if ((t & 63) == 0) red[t >> 6] = m;
  __syncthreads();
  m = fmaxf(fmaxf(red[0], red[1]), fmaxf(red[2], red[3]));
  __syncthreads();
  s = 0.f;
  for (int i = t; i < LT_; i += 256) { float e = __expf(lqp[i] - m); attq[i] = e; s += e; }
  #pragma unroll
  for (int o = 32; o > 0; o >>= 1) s += __shfl_down(s, o, 64);
  if ((t & 63) == 0) red[t >> 6] = s;
  __syncthreads();
  s = red[0] + red[1] + red[2] + red[3];
  {
    float inv = 1.f / s;
    for (int i = t; i < LT_; i += 256) attq[i] *= inv;
  }
  __syncthreads();

  // ---- context vectors ----
  const float* ip = image + (long)b * LI_ * D_;
  const float* tp = text  + (long)b * LT_ * D_;
  float* hp = head + ((long)h * B_ + b) * D_;
  for (int d = t; d < D_; d += 256) {
    float cv = 0.f, cq = 0.f;
    for (int y = 0; y < LI_; ++y) cv = fmaf(attv[y], ip[(long)y * D_ + d], cv);
    for (int x = 0; x < LT_; ++x) cq = fmaf(attq[x], tp[(long)x * D_ + d], cq);
    hp[d] = cv + cq;
  }
}

// out[b,d] = bo[d] + sum_{h,e} head[h,b,e] * Wo[d, h*D+e]   (one block per d)
__global__ __launch_bounds__(256) void out_proj(
    const float* __restrict__ head, const float* __restrict__ Wo,
    const float* __restrict__ bo, float* __restrict__ out)
{
  const int d = blockIdx.x, t = threadIdx.x;
  float acc[B_];
  #pragma unroll
  for (int b = 0; b < B_; ++b) acc[b] = 0.f;
  const float* wrow = Wo + (long)d * (H_ * D_);
  for (int k = t; k < H_ * D_; k += 256) {
    float w = wrow[k];
    int h = k / D_, e = k - h * D_;
    const float* hp = head + (long)h * B_ * D_ + e;
    #pragma unroll
    for (int b = 0; b < B_; ++b) acc[b] = fmaf(w, hp[(long)b * D_], acc[b]);
  }
  __shared__ float red[4][B_];
  const int w4 = t >> 6;
  #pragma unroll
  for (int b = 0; b < B_; ++b) {
    float v = acc[b];
    #pragma unroll
    for (int o = 32; o > 0; o >>= 1) v += __shfl_down(v, o, 64);
    if ((t & 63) == 0) red[w4][b] = v;
  }
  __syncthreads();
  if (t < B_)
    out[(long)t * D_ + d] = red[0][t] + red[1][t] + red[2][t] + red[3][t] + bo[d];
}

extern "C" void kernel_launch(void* const* d_in, const int* in_sizes, int n_in,
                              void* d_out, int out_size, void* d_ws, size_t ws_size,
                              hipStream_t stream)
{
  const float* text  = (const float*)d_in[0];
  const float* image = (const float*)d_in[1];
  // d_in[2] = text_mask (all ones; unused by reference)
  const float* Wb  = (const float*)d_in[3];
  const float* Wv  = (const float*)d_in[4];
  const float* Wq  = (const float*)d_in[5];
  const float* Whv = (const float*)d_in[6];
  const float* Whq = (const float*)d_in[7];
  const float* Wo  = (const float*)d_in[8];
  const float* bo  = (const float*)d_in[9];
  float* out = (float*)d_out;

  // workspace layout (floats)
  const long N_WVV  = (long)B_ * LI_ * K_;   // 9437184
  const long N_WQQ  = (long)B_ * LT_ * K_;   // 8388608
  const long N_PT   = (long)B_ * LT_ * D_;   // 12582912
  const long N_AFF  = (long)B_ * LT_ * LI_;  // 9437184
  const long N_WQQC = (long)B_ * LI_ * K_;   // 9437184
  const long N_WVVC = (long)B_ * LT_ * K_;   // 8388608
  const long N_LV   = (long)H_ * B_ * LI_;   // 147456
  const long N_LQ   = (long)H_ * B_ * LT_;   // 131072
  const long N_HEAD = (long)H_ * B_ * D_;    // 196608
  const long total_floats = N_WVV + N_WQQ + N_PT + N_AFF + N_WQQC + N_WVVC + N_LV + N_LQ + N_HEAD;
  if (ws_size < (size_t)total_floats * sizeof(float)) return;  // scratch too small: bail (visible as validation failure)

  float* ws    = (float*)d_ws;
  float* wv_v  = ws;
  float* wq_q  = wv_v + N_WVV;
  float* pt    = wq_q + N_WQQ;
  float* aff   = pt   + N_PT;
  float* wqqc  = aff  + N_AFF;
  float* wvvc  = wqqc + N_WQQC;
  float* lv    = wvvc + N_WVVC;
  float* lq    = lv   + N_LV;
  float* head  = lq   + N_LQ;

  dim3 blk(256);

  // wv_v[b,y,k] = sum_e image[b,y,e] * Wv[k,e]      (NT, batch folded into rows)
  gemm_kern<0><<<dim3((B_ * LI_) / TBM, K_ / TBN, 1), blk, 0, stream>>>(
      image, Wv, wv_v, D_, D_, D_, K_, 0, 0, 0);
  // wq_q[b,x,k] = sum_e text[b,x,e] * Wq[k,e]
  gemm_kern<0><<<dim3((B_ * LT_) / TBM, K_ / TBN, 1), blk, 0, stream>>>(
      text, Wq, wq_q, D_, D_, D_, K_, 0, 0, 0);

  for (int h = 0; h < H_; ++h) {
    // pt[b,x,e] = sum_f text[b,x,f] * Wb[h,e,f]     (NT)
    gemm_kern<0><<<dim3((B_ * LT_) / TBM, D_ / TBN, 1), blk, 0, stream>>>(
        text, Wb + (long)h * D_ * D_, pt, D_, D_, D_, D_, 0, 0, 0);
    // aff[b,x,y] = sum_e pt[b,x,e] * image[b,y,e]   (NT, batched over b)
    gemm_kern<0><<<dim3(LT_ / TBM, LI_ / TBN, B_), blk, 0, stream>>>(
        pt, image, aff, D_, D_, D_, LI_,
        (long)LT_ * D_, (long)LI_ * D_, (long)LT_ * LI_);
    // wqqc[b,y,k] = sum_x aff[b,x,y] * wq_q[b,x,k]  (TN, batched over b)
    gemm_kern<1><<<dim3(LI_ / TBM, K_ / TBN, B_), blk, 0, stream>>>(
        aff, wq_q, wqqc, LT_, LI_, K_, K_,
        (long)LT_ * LI_, (long)LT_ * K_, (long)LI_ * K_);
    // wvvc[b,x,k] = sum_y aff[b,x,y] * wv_v[b,y,k]  (NN, batched over b)
    gemm_kern<2><<<dim3(LT_ / TBM, K_ / TBN, B_), blk, 0, stream>>>(
        aff, wv_v, wvvc, LI_, LI_, K_, K_,
        (long)LT_ * LI_, (long)LI_ * K_, (long)LT_ * K_);
    // lv[h,b,y] = sum_k tanh(wv_v + wqqc) * Whv[k]
    tanh_dot<<<B_ * LI_, blk, 0, stream>>>(wv_v, wqqc, Whv, lv + (long)h * B_ * LI_, K_);
    // lq[h,b,x] = sum_k tanh(wq_q + wvvc) * Whq[k]
    tanh_dot<<<B_ * LT_, blk, 0, stream>>>(wq_q, wvvc, Whq, lq + (long)h * B_ * LT_, K_);
  }

  // softmaxes + context vectors -> head[h,b,d]
  softmax_ctx<<<dim3(B_, H_), blk, 0, stream>>>(lv, lq, image, text, head);
  // final projection
  out_proj<<<D_, blk, 0, stream>>>(head, Wo, bo, out);
}

// Round 2
// 1995.857 us; speedup vs baseline: 3.5288x; 3.5288x over previous
//
#include <hip/hip_runtime.h>
#include <math.h>

#define B_  32
#define LT_ 512
#define LI_ 576
#define LIP 640           // image tokens padded to a multiple of 128
#define D_  768
#define H_  8
#define K_  512

typedef __attribute__((ext_vector_type(8))) short short8;
typedef __attribute__((ext_vector_type(8))) unsigned short ushort8;
typedef __attribute__((ext_vector_type(4))) float f32x4;

__device__ __forceinline__ unsigned short f2bf(float x) {
  unsigned u = __float_as_uint(x);
  return (unsigned short)((u + 0x7fffu + ((u >> 16) & 1u)) >> 16);  // RNE
}
__device__ __forceinline__ float bf2f(unsigned short u) {
  return __uint_as_float(((unsigned)u) << 16);
}

__device__ __forceinline__ void gl_lds16(const void* g, void* l) {
  __builtin_amdgcn_global_load_lds(
      (const __attribute__((address_space(1))) void*)g,
      (__attribute__((address_space(3))) void*)l, 16, 0, 0);
}

// ---------------------------------------------------------------------------
// NT bf16 MFMA GEMM: C[m,n] = sum_k A[m*Kd+k]*B[n*Kd+k]
// 128x128 tile, BK=32, 256 threads (4 waves, 2x2 of 64x64), m97 structure.
// LDS tiles [row][k] with k-slot XOR swizzle: slot = chunk ^ ((row>>1)&3),
// applied identically on the (pre-swizzled global source -> linear LDS) write
// and on the ds_read side (rule #21: both-sides-or-neither).
// EPI 0: store bf16 C.  EPI 1: fused tanh-dot epilogue:
//   out[row] += sum_col tanh(bf2f(base[row,col]) + acc) * wvec[col]
// ---------------------------------------------------------------------------
#define EPI_BF16 0
#define EPI_TANH 1

template<int EPI>
__global__ __launch_bounds__(256) void mfma_nt(
    const unsigned short* __restrict__ Ag, const unsigned short* __restrict__ Bg,
    unsigned short* __restrict__ Cg, int Kd, long sA, long sB, long sC,
    const unsigned short* __restrict__ baseg, long sBase,
    const float* __restrict__ wvec, float* __restrict__ outv, int valid_rows)
{
  __shared__ unsigned short As[128 * 32];
  __shared__ unsigned short Bs[128 * 32];
  const int t = threadIdx.x;
  const int lane = t & 63, w = t >> 6;
  const int wr = w >> 1, wc = w & 1;
  const int m0 = blockIdx.x * 128, n0 = blockIdx.y * 128;
  const int ldc = (int)gridDim.y * 128;
  const unsigned short* A  = Ag + (long)blockIdx.z * sA;
  const unsigned short* Bm = Bg + (long)blockIdx.z * sB;

  // staging: wave w owns 16-row chunks {w, w+4} of each 128x32 tile.
  // lane l -> row = c*16 + (l>>2), kslot = l&3 ; LDS linear dest = base + l*16B
  // content pre-swizzled on the global side: k-chunk = kslot ^ ((row>>1)&3)
  const int srow0 = w * 16 + (lane >> 2);
  const int srow1 = srow0 + 64;
  const int kc0 = (lane & 3) ^ ((srow0 >> 1) & 3);
  const int kc1 = (lane & 3) ^ ((srow1 >> 1) & 3);
  const unsigned short* a0 = A  + (long)(m0 + srow0) * Kd + kc0 * 8;
  const unsigned short* a1 = A  + (long)(m0 + srow1) * Kd + kc1 * 8;
  const unsigned short* b0 = Bm + (long)(n0 + srow0) * Kd + kc0 * 8;
  const unsigned short* b1 = Bm + (long)(n0 + srow1) * Kd + kc1 * 8;
  unsigned short* asb0 = As + w * 512;        // chunk c -> c*1024 bytes
  unsigned short* asb1 = As + (w + 4) * 512;
  unsigned short* bsb0 = Bs + w * 512;
  unsigned short* bsb1 = Bs + (w + 4) * 512;

  f32x4 acc[4][4];
  #pragma unroll
  for (int i = 0; i < 4; ++i)
    #pragma unroll
    for (int j = 0; j < 4; ++j)
      acc[i][j] = (f32x4){0.f, 0.f, 0.f, 0.f};

  const int rl = lane & 15, g = lane >> 4;
  // row = (multiple of 16) + rl  =>  (row>>1)&3 == (rl>>1)&3
  const int aslot = ((g ^ ((rl >> 1) & 3)) << 3);

  for (int k0 = 0; k0 < Kd; k0 += 32) {
    __syncthreads();                 // previous compute done -> LDS reusable
    gl_lds16(a0 + k0, asb0);
    gl_lds16(a1 + k0, asb1);
    gl_lds16(b0 + k0, bsb0);
    gl_lds16(b1 + k0, bsb1);
    __syncthreads();                 // vmcnt(0) drain -> tile resident
    short8 af[4], bf[4];
    #pragma unroll
    for (int i = 0; i < 4; ++i) {
      af[i] = *(const short8*)&As[(wr * 64 + i * 16 + rl) * 32 + aslot];
      bf[i] = *(const short8*)&Bs[(wc * 64 + i * 16 + rl) * 32 + aslot];
    }
    #pragma unroll
    for (int i = 0; i < 4; ++i)
      #pragma unroll
      for (int j = 0; j < 4; ++j)
        acc[i][j] = __builtin_amdgcn_mfma_f32_16x16x32_bf16(af[i], bf[j], acc[i][j], 0, 0, 0);
  }

  const int rg = lane >> 4;
  if (EPI == EPI_BF16) {
    unsigned short* C = Cg + (long)blockIdx.z * sC;
    #pragma unroll
    for (int i = 0; i < 4; ++i)
      #pragma unroll
      for (int j = 0; j < 4; ++j)
        #pragma unroll
        for (int r = 0; r < 4; ++r) {
          int row = m0 + wr * 64 + i * 16 + rg * 4 + r;   // C/D: row=(l>>4)*4+reg
          int col = n0 + wc * 64 + j * 16 + rl;           //      col=l&15
          C[(long)row * ldc + col] = f2bf(acc[i][j][r]);
        }
  } else {
    const unsigned short* base = baseg + (long)blockIdx.z * sBase;
    float* outp = outv + (long)blockIdx.z * valid_rows;
    #pragma unroll
    for (int i = 0; i < 4; ++i)
      #pragma unroll
      for (int r = 0; r < 4; ++r) {
        int row = m0 + wr * 64 + i * 16 + rg * 4 + r;
        float s = 0.f;
        #pragma unroll
        for (int j = 0; j < 4; ++j) {
          int col = n0 + wc * 64 + j * 16 + rl;
          float v = acc[i][j][r] + bf2f(base[(long)row * ldc + col]);
          s += tanhf(v) * wvec[col];
        }
        s += __shfl_xor(s, 1, 64);   // reduce over the 16 col-lanes
        s += __shfl_xor(s, 2, 64);
        s += __shfl_xor(s, 4, 64);
        s += __shfl_xor(s, 8, 64);
        if (rl == 0 && row < valid_rows)
          atomicAdd(&outp[row], s);
      }
  }
}

// --------------------------- helper kernels --------------------------------
__global__ __launch_bounds__(256) void cast_bf16(
    const float* __restrict__ in, unsigned short* __restrict__ out, long n8)
{
  long i = (long)blockIdx.x * 256 + threadIdx.x;
  if (i >= n8) return;
  float4 v0 = ((const float4*)in)[i * 2];
  float4 v1 = ((const float4*)in)[i * 2 + 1];
  ushort8 o;
  o[0] = f2bf(v0.x); o[1] = f2bf(v0.y); o[2] = f2bf(v0.z); o[3] = f2bf(v0.w);
  o[4] = f2bf(v1.x); o[5] = f2bf(v1.y); o[6] = f2bf(v1.z); o[7] = f2bf(v1.w);
  *(ushort8*)(out + i * 8) = o;
}

__global__ __launch_bounds__(256) void cast_pad_image_k(
    const float* __restrict__ in, unsigned short* __restrict__ out)
{
  long tid = (long)blockIdx.x * 256 + threadIdx.x;
  const long tot = (long)B_ * LIP * (D_ / 8);
  if (tid >= tot) return;
  int e8 = (int)(tid % (D_ / 8));
  long rw = tid / (D_ / 8);
  int y  = (int)(rw % LIP);
  long b = rw / LIP;
  ushort8 o;
  if (y < LI_) {
    const float* p = in + ((b * LI_ + y) * D_ + e8 * 8);
    float4 v0 = *(const float4*)p, v1 = *(const float4*)(p + 4);
    o[0] = f2bf(v0.x); o[1] = f2bf(v0.y); o[2] = f2bf(v0.z); o[3] = f2bf(v0.w);
    o[4] = f2bf(v1.x); o[5] = f2bf(v1.y); o[6] = f2bf(v1.z); o[7] = f2bf(v1.w);
  } else {
    #pragma unroll
    for (int j = 0; j < 8; ++j) o[j] = 0;
  }
  *(ushort8*)(out + rw * D_ + e8 * 8) = o;
}

__global__ __launch_bounds__(256) void zero_f32(float* __restrict__ p, long n) {
  long i = (long)blockIdx.x * 256 + threadIdx.x;
  if (i < n) p[i] = 0.f;
}

// per (b,h): softmax(lv) over LI, softmax(lq) over LT, then context vectors
__global__ __launch_bounds__(256) void softmax_ctx(
    const float* __restrict__ lv, const float* __restrict__ lq,
    const float* __restrict__ image, const float* __restrict__ text,
    float* __restrict__ head)
{
  const int b = blockIdx.x, h = blockIdx.y;
  const int t = threadIdx.x;
  __shared__ float attv[LI_];
  __shared__ float attq[LT_];
  __shared__ float red[4];

  const float* lvp = lv + ((long)h * B_ + b) * LI_;
  float m = -1e30f;
  for (int i = t; i < LI_; i += 256) m = fmaxf(m, lvp[i]);
  #pragma unroll
  for (int o = 32; o > 0; o >>= 1) m = fmaxf(m, __shfl_down(m, o, 64));
  if ((t & 63) == 0) red[t >> 6] = m;
  __syncthreads();
  m = fmaxf(fmaxf(red[0], red[1]), fmaxf(red[2], red[3]));
  __syncthreads();
  float s = 0.f;
  for (int i = t; i < LI_; i += 256) { float e = __expf(lvp[i] - m); attv[i] = e; s += e; }
  #pragma unroll
  for (int o = 32; o > 0; o >>= 1) s += __shfl_down(s, o, 64);
  if ((t & 63) == 0) red[t >> 6] = s;
  __syncthreads();
  s = red[0] + red[1] + red[2] + red[3];
  { float inv = 1.f / s; for (int i = t; i < LI_; i += 256) attv[i] *= inv; }
  __syncthreads();

  const float* lqp = lq + ((long)h * B_ + b) * LT_;
  m = -1e30f;
  for (int i = t; i < LT_; i += 256) m = fmaxf(m, lqp[i]);
  #pragma unroll
  for (int o = 32; o > 0; o >>= 1) m = fmaxf(m, __shfl_down(m, o, 64));
  if ((t & 63) == 0) red[t >> 6] = m;
  __syncthreads();
  m = fmaxf(fmaxf(red[0], red[1]), fmaxf(red[2], red[3]));
  __syncthreads();
  s = 0.f;
  for (int i = t; i < LT_; i += 256) { float e = __expf(lqp[i] - m); attq[i] = e; s += e; }
  #pragma unroll
  for (int o = 32; o > 0; o >>= 1) s += __shfl_down(s, o, 64);
  if ((t & 63) == 0) red[t >> 6] = s;
  __syncthreads();
  s = red[0] + red[1] + red[2] + red[3];
  { float inv = 1.f / s; for (int i = t; i < LT_; i += 256) attq[i] *= inv; }
  __syncthreads();

  const float* ip = image + (long)b * LI_ * D_;
  const float* tp = text  + (long)b * LT_ * D_;
  float* hp = head + ((long)h * B_ + b) * D_;
  for (int d = t; d < D_; d += 256) {
    float cv = 0.f, cq = 0.f;
    for (int y = 0; y < LI_; ++y) cv = fmaf(attv[y], ip[(long)y * D_ + d], cv);
    for (int x = 0; x < LT_; ++x) cq = fmaf(attq[x], tp[(long)x * D_ + d], cq);
    hp[d] = cv + cq;
  }
}

// out[b,d] = bo[d] + sum_{h,e} head[h,b,e] * Wo[d, h*D+e]   (one block per d)
__global__ __launch_bounds__(256) void out_proj(
    const float* __restrict__ head, const float* __restrict__ Wo,
    const float* __restrict__ bo, float* __restrict__ out)
{
  const int d = blockIdx.x, t = threadIdx.x;
  float acc[B_];
  #pragma unroll
  for (int b = 0; b < B_; ++b) acc[b] = 0.f;
  const float* wrow = Wo + (long)d * (H_ * D_);
  for (int k = t; k < H_ * D_; k += 256) {
    float wv = wrow[k];
    int h = k / D_, e = k - h * D_;
    const float* hp = head + (long)h * B_ * D_ + e;
    #pragma unroll
    for (int b = 0; b < B_; ++b) acc[b] = fmaf(wv, hp[(long)b * D_], acc[b]);
  }
  __shared__ float red[4][B_];
  const int w4 = t >> 6;
  #pragma unroll
  for (int b = 0; b < B_; ++b) {
    float v = acc[b];
    #pragma unroll
    for (int o = 32; o > 0; o >>= 1) v += __shfl_down(v, o, 64);
    if ((t & 63) == 0) red[w4][b] = v;
  }
  __syncthreads();
  if (t < B_)
    out[(long)t * D_ + d] = red[0][t] + red[1][t] + red[2][t] + red[3][t] + bo[d];
}

// ---------------------------------------------------------------------------
extern "C" void kernel_launch(void* const* d_in, const int* in_sizes, int n_in,
                              void* d_out, int out_size, void* d_ws, size_t ws_size,
                              hipStream_t stream)
{
  const float* text  = (const float*)d_in[0];
  const float* image = (const float*)d_in[1];
  const float* Wb  = (const float*)d_in[3];
  const float* Wv  = (const float*)d_in[4];
  const float* Wq  = (const float*)d_in[5];
  const float* Whv = (const float*)d_in[6];
  const float* Whq = (const float*)d_in[7];
  const float* Wo  = (const float*)d_in[8];
  const float* bo  = (const float*)d_in[9];
  float* out = (float*)d_out;

  // ---- workspace layout (ushort section, then fp32 section) ----
  const long N_TEXT = (long)B_ * LT_ * D_;   // 12,582,912
  const long N_IMGP = (long)B_ * LIP * D_;   // 15,728,640
  const long N_WV   = (long)K_ * D_;         //    393,216
  const long N_WBH  = (long)D_ * D_;         //    589,824
  const long N_WVV  = (long)B_ * LIP * K_;   // 10,485,760
  const long N_WQQ  = (long)B_ * LT_ * K_;   //  8,388,608
  const long N_WVVT = (long)B_ * K_ * LIP;   // 10,485,760
  const long N_WQQT = (long)B_ * K_ * LT_;   //  8,388,608
  const long N_PT   = (long)B_ * LT_ * D_;   // 12,582,912
  const long N_AFF  = (long)B_ * LT_ * LIP;  // 10,485,760
  const long N_LV   = (long)H_ * B_ * LI_;
  const long N_LQ   = (long)H_ * B_ * LT_;
  const long N_HEAD = (long)H_ * B_ * D_;

  unsigned short* wsu = (unsigned short*)d_ws;
  long off = 0;
  unsigned short* text_bf = wsu + off; off += N_TEXT;
  unsigned short* image_p = wsu + off; off += N_IMGP;
  unsigned short* Wv_bf   = wsu + off; off += N_WV;
  unsigned short* Wq_bf   = wsu + off; off += N_WV;
  unsigned short* Wbh_bf  = wsu + off; off += N_WBH;
  unsigned short* wv_v_bf = wsu + off; off += N_WVV;
  unsigned short* wq_q_bf = wsu + off; off += N_WQQ;
  unsigned short* wv_vT   = wsu + off; off += N_WVVT;
  unsigned short* wq_qT   = wsu + off; off += N_WQQT;
  unsigned short* pt_bf   = wsu + off; off += N_PT;
  unsigned short* aff     = wsu + off; off += N_AFF;
  unsigned short* affT    = wsu + off; off += N_AFF;
  float* lv   = (float*)(wsu + off);
  float* lq   = lv + N_LV;
  float* head = lq + N_LQ;
  const size_t need = (size_t)off * 2 + (size_t)(N_LV + N_LQ + N_HEAD) * 4;
  if (ws_size < need) return;

  dim3 blk(256);

  // ---- casts ----
  cast_bf16<<<(unsigned)(N_TEXT / 8 / 256), blk, 0, stream>>>(text, text_bf, N_TEXT / 8);
  cast_pad_image_k<<<(unsigned)((B_ * LIP * (D_ / 8) + 255) / 256), blk, 0, stream>>>(image, image_p);
  cast_bf16<<<(unsigned)(N_WV / 8 / 256), blk, 0, stream>>>(Wv, Wv_bf, N_WV / 8);
  cast_bf16<<<(unsigned)(N_WV / 8 / 256), blk, 0, stream>>>(Wq, Wq_bf, N_WV / 8);
  zero_f32<<<(unsigned)((N_LV + N_LQ + 255) / 256), blk, 0, stream>>>(lv, N_LV + N_LQ);

  // ---- head-shared projections (all NT) ----
  // wv_v[b*640+y, k] = image_p . Wv^T
  mfma_nt<EPI_BF16><<<dim3(160, 4, 1), blk, 0, stream>>>(
      image_p, Wv_bf, wv_v_bf, D_, 0, 0, 0, nullptr, 0, nullptr, nullptr, 0);
  // wq_q[b*512+x, k] = text . Wq^T
  mfma_nt<EPI_BF16><<<dim3(128, 4, 1), blk, 0, stream>>>(
      text_bf, Wq_bf, wq_q_bf, D_, 0, 0, 0, nullptr, 0, nullptr, nullptr, 0);
  // wv_vT[b][k][y] = Wv . image_p[b]^T   (batched, A shared)
  mfma_nt<EPI_BF16><<<dim3(4, 5, B_), blk, 0, stream>>>(
      Wv_bf, image_p, wv_vT, D_, 0, (long)LIP * D_, (long)K_ * LIP,
      nullptr, 0, nullptr, nullptr, 0);
  // wq_qT[b][k][x] = Wq . text[b]^T
  mfma_nt<EPI_BF16><<<dim3(4, 4, B_), blk, 0, stream>>>(
      Wq_bf, text_bf, wq_qT, D_, 0, (long)LT_ * D_, (long)K_ * LT_,
      nullptr, 0, nullptr, nullptr, 0);

  for (int h = 0; h < H_; ++h) {
    cast_bf16<<<(unsigned)(N_WBH / 8 / 256), blk, 0, stream>>>(
        Wb + (long)h * D_ * D_, Wbh_bf, N_WBH / 8);
    // pt[b*512+x, e] = text . Wb[h]^T
    mfma_nt<EPI_BF16><<<dim3(128, 6, 1), blk, 0, stream>>>(
        text_bf, Wbh_bf, pt_bf, D_, 0, 0, 0, nullptr, 0, nullptr, nullptr, 0);
    // aff[b][x][y] = pt[b] . image_p[b]^T
    mfma_nt<EPI_BF16><<<dim3(4, 5, B_), blk, 0, stream>>>(
        pt_bf, image_p, aff, D_, (long)LT_ * D_, (long)LIP * D_, (long)LT_ * LIP,
        nullptr, 0, nullptr, nullptr, 0);
    // affT[b][y][x] = image_p[b] . pt[b]^T
    mfma_nt<EPI_BF16><<<dim3(5, 4, B_), blk, 0, stream>>>(
        image_p, pt_bf, affT, D_, (long)LIP * D_, (long)LT_ * D_, (long)LIP * LT_,
        nullptr, 0, nullptr, nullptr, 0);
    // wqqc[b][y][k] = affT[b] . wq_qT[b]^T ; fused: lv[h,b,y] += tanh(wv_v+wqqc).Whv
    mfma_nt<EPI_TANH><<<dim3(5, 4, B_), blk, 0, stream>>>(
        affT, wq_qT, nullptr, LT_, (long)LIP * LT_, (long)K_ * LT_, 0,
        wv_v_bf, (long)LIP * K_, Whv, lv + (long)h * B_ * LI_, LI_);
    // wvvc[b][x][k] = aff[b] . wv_vT[b]^T ; fused: lq[h,b,x] += tanh(wq_q+wvvc).Whq
    mfma_nt<EPI_TANH><<<dim3(4, 4, B_), blk, 0, stream>>>(
        aff, wv_vT, nullptr, LIP, (long)LT_ * LIP, (long)K_ * LIP, 0,
        wq_q_bf, (long)LT_ * K_, Whq, lq + (long)h * B_ * LT_, LT_);
  }

  softmax_ctx<<<dim3(B_, H_), blk, 0, stream>>>(lv, lq, image, text, head);
  out_proj<<<D_, blk, 0, stream>>>(head, Wo, bo, out);
}

// Round 3
// 1364.643 us; speedup vs baseline: 5.1611x; 1.4625x over previous
//
#include <hip/hip_runtime.h>
#include <math.h>

#define B_  32
#define LT_ 512
#define LI_ 576
#define LIP 640           // image tokens padded to a multiple of 128
#define D_  768
#define H_  8
#define K_  512

typedef __attribute__((ext_vector_type(8))) short short8;
typedef __attribute__((ext_vector_type(4))) short short4v;
typedef __attribute__((ext_vector_type(8))) unsigned short ushort8;
typedef __attribute__((ext_vector_type(8))) _Float16 f16x8;
typedef __attribute__((ext_vector_type(4))) float f32x4;

__device__ __forceinline__ unsigned short f2h(float x) {
  _Float16 h = (_Float16)x;                       // RNE
  return __builtin_bit_cast(unsigned short, h);
}
__device__ __forceinline__ float h2f(unsigned short u) {
  return (float)__builtin_bit_cast(_Float16, u);
}
__device__ __forceinline__ float ftanh(float x) {
  float e = __expf(2.f * x);                      // saturates to +inf / 0 correctly
  return 1.f - 2.f / (e + 1.f);
}

__device__ __forceinline__ void gl_lds16(const void* g, void* l) {
  __builtin_amdgcn_global_load_lds(
      (const __attribute__((address_space(1))) void*)g,
      (__attribute__((address_space(3))) void*)l, 16, 0, 0);
}

// ---------------------------------------------------------------------------
// NT fp16 MFMA GEMM: C[m,n] = sum_k A[m*Kd+k]*B[n*Kd+k]
// 128x128 tile, BK=32, 4 waves (2x2 of 64x64), m97 structure, XCD-swizzled
// 1D grid (bijective m204 remap), LDS k-slot XOR swizzle on both sides.
// EPI_PLAIN: store fp16 C.
// EPI_T:     store fp16 C and C^T (padded-LDS transpose, ld=136).
// EPI_TANH:  out[row] += sum_col ftanh(h2f(base[row,col]) + acc) * wvec[col]
// ---------------------------------------------------------------------------
#define EPI_PLAIN 0
#define EPI_T     1
#define EPI_TANH  2

template<int EPI>
__global__ __launch_bounds__(256) void mfma_nt(
    const unsigned short* __restrict__ Ag, const unsigned short* __restrict__ Bg,
    unsigned short* __restrict__ Cg, unsigned short* __restrict__ CTg,
    int Kd, int gx, int gy,
    long sA, long sB, long sC, long sCT,
    const unsigned short* __restrict__ baseg, long sBase,
    const float* __restrict__ wvec, float* __restrict__ outv, int valid_rows)
{
  // --- bijective XCD-aware swizzle of the 1D grid (m204) ---
  const int orig = blockIdx.x, nwg = gridDim.x;
  const int q = nwg >> 3, r = nwg & 7;
  const int xcd = orig & 7, idx = orig >> 3;
  const int wg = (xcd < r ? xcd * (q + 1) : r * (q + 1) + (xcd - r) * q) + idx;
  const int bx = wg % gx, tmp = wg / gx, by = tmp % gy, bz = tmp / gy;

  __shared__ unsigned short As[128 * 32];
  __shared__ unsigned short Bs[128 * 32];
  __shared__ unsigned short T[EPI == EPI_T ? 128 * 136 : 8];

  const int t = threadIdx.x;
  const int lane = t & 63, w = t >> 6;
  const int wr = w >> 1, wc = w & 1;
  const int m0 = bx * 128, n0 = by * 128;
  const int ldc = gy << 7;
  const unsigned short* A  = Ag + (long)bz * sA;
  const unsigned short* Bm = Bg + (long)bz * sB;

  const int srow0 = w * 16 + (lane >> 2);
  const int srow1 = srow0 + 64;
  const int kc0 = (lane & 3) ^ ((srow0 >> 1) & 3);
  const int kc1 = (lane & 3) ^ ((srow1 >> 1) & 3);
  const unsigned short* a0 = A  + (long)(m0 + srow0) * Kd + kc0 * 8;
  const unsigned short* a1 = A  + (long)(m0 + srow1) * Kd + kc1 * 8;
  const unsigned short* b0 = Bm + (long)(n0 + srow0) * Kd + kc0 * 8;
  const unsigned short* b1 = Bm + (long)(n0 + srow1) * Kd + kc1 * 8;
  unsigned short* asb0 = As + w * 512;
  unsigned short* asb1 = As + (w + 4) * 512;
  unsigned short* bsb0 = Bs + w * 512;
  unsigned short* bsb1 = Bs + (w + 4) * 512;

  f32x4 acc[4][4];
  #pragma unroll
  for (int i = 0; i < 4; ++i)
    #pragma unroll
    for (int j = 0; j < 4; ++j)
      acc[i][j] = (f32x4){0.f, 0.f, 0.f, 0.f};

  const int rl = lane & 15, g = lane >> 4;
  const int aslot = ((g ^ ((rl >> 1) & 3)) << 3);

  for (int k0 = 0; k0 < Kd; k0 += 32) {
    __syncthreads();
    gl_lds16(a0 + k0, asb0);
    gl_lds16(a1 + k0, asb1);
    gl_lds16(b0 + k0, bsb0);
    gl_lds16(b1 + k0, bsb1);
    __syncthreads();
    f16x8 af[4], bf[4];
    #pragma unroll
    for (int i = 0; i < 4; ++i) {
      af[i] = *(const f16x8*)&As[(wr * 64 + i * 16 + rl) * 32 + aslot];
      bf[i] = *(const f16x8*)&Bs[(wc * 64 + i * 16 + rl) * 32 + aslot];
    }
    #pragma unroll
    for (int i = 0; i < 4; ++i)
      #pragma unroll
      for (int j = 0; j < 4; ++j)
        acc[i][j] = __builtin_amdgcn_mfma_f32_16x16x32_f16(af[i], bf[j], acc[i][j], 0, 0, 0);
  }

  const int rg = lane >> 4;
  if (EPI != EPI_TANH) {
    unsigned short* C = Cg + (long)bz * sC;
    #pragma unroll
    for (int i = 0; i < 4; ++i)
      #pragma unroll
      for (int j = 0; j < 4; ++j) {
        unsigned short hv[4];
        #pragma unroll
        for (int rr = 0; rr < 4; ++rr) {
          int row = wr * 64 + i * 16 + rg * 4 + rr;      // m-local
          int col = wc * 64 + j * 16 + rl;               // n-local
          hv[rr] = f2h(acc[i][j][rr]);
          C[(long)(m0 + row) * ldc + n0 + col] = hv[rr];
        }
        if (EPI == EPI_T) {
          int col = wc * 64 + j * 16 + rl;
          int row0 = wr * 64 + i * 16 + rg * 4;
          *(short4v*)&T[col * 136 + row0] =
              (short4v){(short)hv[0], (short)hv[1], (short)hv[2], (short)hv[3]};
        }
      }
    if (EPI == EPI_T) {
      __syncthreads();
      unsigned short* CT = CTg + (long)bz * sCT;
      const int ldTm = gx << 7;
      #pragma unroll
      for (int rr = 0; rr < 8; ++rr) {
        int rn = rr * 16 + (t >> 4);      // n-local
        int c8 = (t & 15) * 8;            // m-local
        *(ushort8*)(CT + (long)(n0 + rn) * ldTm + m0 + c8) = *(const ushort8*)&T[rn * 136 + c8];
      }
    }
  } else {
    const unsigned short* base = baseg + (long)bz * sBase;
    float* outp = outv + (long)bz * valid_rows;
    #pragma unroll
    for (int i = 0; i < 4; ++i)
      #pragma unroll
      for (int rr = 0; rr < 4; ++rr) {
        int row = m0 + wr * 64 + i * 16 + rg * 4 + rr;
        float s = 0.f;
        #pragma unroll
        for (int j = 0; j < 4; ++j) {
          int col = n0 + wc * 64 + j * 16 + rl;
          float v = acc[i][j][rr] + h2f(base[(long)row * ldc + col]);
          s += ftanh(v) * wvec[col];
        }
        s += __shfl_xor(s, 1, 64);
        s += __shfl_xor(s, 2, 64);
        s += __shfl_xor(s, 4, 64);
        s += __shfl_xor(s, 8, 64);
        if (rl == 0 && row < valid_rows)
          atomicAdd(&outp[row], s);
      }
  }
}

// --------------------------- helper kernels --------------------------------
__global__ __launch_bounds__(256) void cast_f16(
    const float* __restrict__ in, unsigned short* __restrict__ out, long n8)
{
  long i = (long)blockIdx.x * 256 + threadIdx.x;
  if (i >= n8) return;
  float4 v0 = ((const float4*)in)[i * 2];
  float4 v1 = ((const float4*)in)[i * 2 + 1];
  ushort8 o;
  o[0] = f2h(v0.x); o[1] = f2h(v0.y); o[2] = f2h(v0.z); o[3] = f2h(v0.w);
  o[4] = f2h(v1.x); o[5] = f2h(v1.y); o[6] = f2h(v1.z); o[7] = f2h(v1.w);
  *(ushort8*)(out + i * 8) = o;
}

__global__ __launch_bounds__(256) void cast_pad_image(
    const float* __restrict__ in, unsigned short* __restrict__ out)
{
  long tid = (long)blockIdx.x * 256 + threadIdx.x;
  const long tot = (long)B_ * LIP * (D_ / 8);
  if (tid >= tot) return;
  int e8 = (int)(tid % (D_ / 8));
  long rw = tid / (D_ / 8);
  int y  = (int)(rw % LIP);
  long b = rw / LIP;
  ushort8 o;
  if (y < LI_) {
    const float* p = in + ((b * LI_ + y) * D_ + e8 * 8);
    float4 v0 = *(const float4*)p, v1 = *(const float4*)(p + 4);
    o[0] = f2h(v0.x); o[1] = f2h(v0.y); o[2] = f2h(v0.z); o[3] = f2h(v0.w);
    o[4] = f2h(v1.x); o[5] = f2h(v1.y); o[6] = f2h(v1.z); o[7] = f2h(v1.w);
  } else {
    #pragma unroll
    for (int j = 0; j < 8; ++j) o[j] = 0;
  }
  *(ushort8*)(out + rw * D_ + e8 * 8) = o;
}

__global__ __launch_bounds__(256) void zero_f32(float* __restrict__ p, long n) {
  long i = (long)blockIdx.x * 256 + threadIdx.x;
  if (i < n) p[i] = 0.f;
}

// per (b,h): softmax over LI (lv) and LT (lq) -> normalized att weights
__global__ __launch_bounds__(256) void softmax_att(
    const float* __restrict__ lv, const float* __restrict__ lq,
    float* __restrict__ attvG, float* __restrict__ attqG)
{
  const int b = blockIdx.x, h = blockIdx.y;
  const int t = threadIdx.x;
  __shared__ float buf[LI_];
  __shared__ float red[4];

  const float* lvp = lv + ((long)h * B_ + b) * LI_;
  float m = -1e30f;
  for (int i = t; i < LI_; i += 256) m = fmaxf(m, lvp[i]);
  #pragma unroll
  for (int o = 32; o > 0; o >>= 1) m = fmaxf(m, __shfl_down(m, o, 64));
  if ((t & 63) == 0) red[t >> 6] = m;
  __syncthreads();
  m = fmaxf(fmaxf(red[0], red[1]), fmaxf(red[2], red[3]));
  __syncthreads();
  float s = 0.f;
  for (int i = t; i < LI_; i += 256) { float e = __expf(lvp[i] - m); buf[i] = e; s += e; }
  #pragma unroll
  for (int o = 32; o > 0; o >>= 1) s += __shfl_down(s, o, 64);
  if ((t & 63) == 0) red[t >> 6] = s;
  __syncthreads();
  s = red[0] + red[1] + red[2] + red[3];
  {
    float inv = 1.f / s;
    float* op = attvG + ((long)h * B_ + b) * LI_;
    for (int i = t; i < LI_; i += 256) op[i] = buf[i] * inv;
  }
  __syncthreads();

  const float* lqp = lq + ((long)h * B_ + b) * LT_;
  m = -1e30f;
  for (int i = t; i < LT_; i += 256) m = fmaxf(m, lqp[i]);
  #pragma unroll
  for (int o = 32; o > 0; o >>= 1) m = fmaxf(m, __shfl_down(m, o, 64));
  if ((t & 63) == 0) red[t >> 6] = m;
  __syncthreads();
  m = fmaxf(fmaxf(red[0], red[1]), fmaxf(red[2], red[3]));
  __syncthreads();
  s = 0.f;
  for (int i = t; i < LT_; i += 256) { float e = __expf(lqp[i] - m); buf[i] = e; s += e; }
  #pragma unroll
  for (int o = 32; o > 0; o >>= 1) s += __shfl_down(s, o, 64);
  if ((t & 63) == 0) red[t >> 6] = s;
  __syncthreads();
  s = red[0] + red[1] + red[2] + red[3];
  {
    float inv = 1.f / s;
    float* op = attqG + ((long)h * B_ + b) * LT_;
    for (int i = t; i < LT_; i += 256) op[i] = buf[i] * inv;
  }
}

// head[h,b,d] = sum_y attv[h,b,y]*image[b,y,d] + sum_x attq[h,b,x]*text[b,x,d]
// grid (B, D/128); 256 thr = 128 d-lanes x 2 token-groups; acc[8 heads]/thread
__global__ __launch_bounds__(256) void ctx_head(
    const float* __restrict__ attvG, const float* __restrict__ attqG,
    const float* __restrict__ image, const float* __restrict__ text,
    float* __restrict__ head)
{
  const int b = blockIdx.x, d0 = blockIdx.y * 128;
  const int t = threadIdx.x;
  const int dl = t & 127, g = t >> 7;
  __shared__ float av[H_][LI_];
  __shared__ float aq[H_][LT_];
  __shared__ float red[H_][128];
  for (int i = t; i < H_ * LI_; i += 256)
    av[i / LI_][i % LI_] = attvG[((long)(i / LI_) * B_ + b) * LI_ + (i % LI_)];
  for (int i = t; i < H_ * LT_; i += 256)
    aq[i / LT_][i % LT_] = attqG[((long)(i / LT_) * B_ + b) * LT_ + (i % LT_)];
  __syncthreads();
  float acc[H_];
  #pragma unroll
  for (int h = 0; h < H_; ++h) acc[h] = 0.f;
  const float* ip = image + (long)b * LI_ * D_ + d0 + dl;
  for (int y = g; y < LI_; y += 2) {
    float val = ip[(long)y * D_];
    #pragma unroll
    for (int h = 0; h < H_; ++h) acc[h] = fmaf(av[h][y], val, acc[h]);
  }
  const float* tp = text + (long)b * LT_ * D_ + d0 + dl;
  for (int x = g; x < LT_; x += 2) {
    float val = tp[(long)x * D_];
    #pragma unroll
    for (int h = 0; h < H_; ++h) acc[h] = fmaf(aq[h][x], val, acc[h]);
  }
  if (g == 1) {
    #pragma unroll
    for (int h = 0; h < H_; ++h) red[h][dl] = acc[h];
  }
  __syncthreads();
  if (g == 0) {
    #pragma unroll
    for (int h = 0; h < H_; ++h)
      head[((long)h * B_ + b) * D_ + d0 + dl] = acc[h] + red[h][dl];
  }
}

// out[b,d] = bo[d] + sum_{h,e} head[h,b,e] * Wo[d, h*D+e]   (one block per d)
__global__ __launch_bounds__(256) void out_proj(
    const float* __restrict__ head, const float* __restrict__ Wo,
    const float* __restrict__ bo, float* __restrict__ out)
{
  const int d = blockIdx.x, t = threadIdx.x;
  float acc[B_];
  #pragma unroll
  for (int b = 0; b < B_; ++b) acc[b] = 0.f;
  const float4* wrow4 = (const float4*)(Wo + (long)d * (H_ * D_));
  for (int k4 = t; k4 < H_ * D_ / 4; k4 += 256) {
    float4 wv = wrow4[k4];
    int k = k4 * 4;
    int h = k / D_, e = k - h * D_;     // D_%4==0: k..k+3 stay in one head
    const float* hp = head + (long)h * B_ * D_ + e;
    #pragma unroll
    for (int b = 0; b < B_; ++b) {
      const float* p = hp + (long)b * D_;
      acc[b] += wv.x * p[0] + wv.y * p[1] + wv.z * p[2] + wv.w * p[3];
    }
  }
  __shared__ float red[4][B_];
  const int w4 = t >> 6;
  #pragma unroll
  for (int b = 0; b < B_; ++b) {
    float v = acc[b];
    #pragma unroll
    for (int o = 32; o > 0; o >>= 1) v += __shfl_down(v, o, 64);
    if ((t & 63) == 0) red[w4][b] = v;
  }
  __syncthreads();
  if (t < B_)
    out[(long)t * D_ + d] = red[0][t] + red[1][t] + red[2][t] + red[3][t] + bo[d];
}

// ---------------------------------------------------------------------------
extern "C" void kernel_launch(void* const* d_in, const int* in_sizes, int n_in,
                              void* d_out, int out_size, void* d_ws, size_t ws_size,
                              hipStream_t stream)
{
  const float* text  = (const float*)d_in[0];
  const float* image = (const float*)d_in[1];
  const float* Wb  = (const float*)d_in[3];
  const float* Wv  = (const float*)d_in[4];
  const float* Wq  = (const float*)d_in[5];
  const float* Whv = (const float*)d_in[6];
  const float* Whq = (const float*)d_in[7];
  const float* Wo  = (const float*)d_in[8];
  const float* bo  = (const float*)d_in[9];
  float* out = (float*)d_out;

  const long N_TEXT = (long)B_ * LT_ * D_;
  const long N_IMGP = (long)B_ * LIP * D_;
  const long N_WV   = (long)K_ * D_;
  const long N_WB   = (long)H_ * D_ * D_;
  const long N_WVV  = (long)B_ * LIP * K_;
  const long N_WQQ  = (long)B_ * LT_ * K_;
  const long N_PT   = (long)B_ * LT_ * D_;
  const long N_AFF  = (long)B_ * LT_ * LIP;
  const long N_LV   = (long)H_ * B_ * LI_;
  const long N_LQ   = (long)H_ * B_ * LT_;
  const long N_HEAD = (long)H_ * B_ * D_;

  unsigned short* wsu = (unsigned short*)d_ws;
  long off = 0;
  unsigned short* text_h  = wsu + off; off += N_TEXT;
  unsigned short* image_p = wsu + off; off += N_IMGP;
  unsigned short* Wv_h    = wsu + off; off += N_WV;
  unsigned short* Wq_h    = wsu + off; off += N_WV;
  unsigned short* Wb_h    = wsu + off; off += N_WB;
  unsigned short* wv_v    = wsu + off; off += N_WVV;
  unsigned short* wq_q    = wsu + off; off += N_WQQ;
  unsigned short* wv_vT   = wsu + off; off += N_WVV;
  unsigned short* wq_qT   = wsu + off; off += N_WQQ;
  unsigned short* pt_h    = wsu + off; off += N_PT;
  unsigned short* aff     = wsu + off; off += N_AFF;
  unsigned short* affT    = wsu + off; off += N_AFF;
  float* lv    = (float*)(wsu + off);
  float* lq    = lv + N_LV;
  float* attvG = lq + N_LQ;
  float* attqG = attvG + N_LV;
  float* head  = attqG + N_LQ;
  const size_t need = (size_t)off * 2 + (size_t)(2 * (N_LV + N_LQ) + N_HEAD) * 4;
  if (ws_size < need) return;

  dim3 blk(256);

  cast_f16<<<(unsigned)(N_TEXT / 8 / 256), blk, 0, stream>>>(text, text_h, N_TEXT / 8);
  cast_pad_image<<<(unsigned)((B_ * LIP * (D_ / 8) + 255) / 256), blk, 0, stream>>>(image, image_p);
  cast_f16<<<(unsigned)(N_WV / 8 / 256), blk, 0, stream>>>(Wv, Wv_h, N_WV / 8);
  cast_f16<<<(unsigned)(N_WV / 8 / 256), blk, 0, stream>>>(Wq, Wq_h, N_WV / 8);
  cast_f16<<<(unsigned)(N_WB / 8 / 256), blk, 0, stream>>>(Wb, Wb_h, N_WB / 8);
  zero_f32<<<(unsigned)((N_LV + N_LQ + 255) / 256), blk, 0, stream>>>(lv, N_LV + N_LQ);

  // wv_v[b][y][k] = image_p[b] . Wv^T  (+ transpose wv_vT[b][k][y])
  mfma_nt<EPI_T><<<5 * 4 * B_, blk, 0, stream>>>(
      image_p, Wv_h, wv_v, wv_vT, D_, 5, 4,
      (long)LIP * D_, 0, (long)LIP * K_, (long)K_ * LIP,
      nullptr, 0, nullptr, nullptr, 0);
  // wq_q[b][x][k] = text[b] . Wq^T  (+ transpose)
  mfma_nt<EPI_T><<<4 * 4 * B_, blk, 0, stream>>>(
      text_h, Wq_h, wq_q, wq_qT, D_, 4, 4,
      (long)LT_ * D_, 0, (long)LT_ * K_, (long)K_ * LT_,
      nullptr, 0, nullptr, nullptr, 0);

  for (int h = 0; h < H_; ++h) {
    // pt[b*512+x, e] = text . Wb[h]^T
    mfma_nt<EPI_PLAIN><<<128 * 6, blk, 0, stream>>>(
        text_h, Wb_h + (long)h * D_ * D_, pt_h, nullptr, D_, 128, 6,
        0, 0, 0, 0, nullptr, 0, nullptr, nullptr, 0);
    // aff[b][x][y] = pt[b] . image_p[b]^T  (+ transpose affT[b][y][x])
    mfma_nt<EPI_T><<<4 * 5 * B_, blk, 0, stream>>>(
        pt_h, image_p, aff, affT, D_, 4, 5,
        (long)LT_ * D_, (long)LIP * D_, (long)LT_ * LIP, (long)LIP * LT_,
        nullptr, 0, nullptr, nullptr, 0);
    // wqqc[b][y][k] = affT[b] . wq_qT[b]^T ; fused lv[h,b,y] += tanh(wv_v+acc).Whv
    mfma_nt<EPI_TANH><<<5 * 4 * B_, blk, 0, stream>>>(
        affT, wq_qT, nullptr, nullptr, LT_, 5, 4,
        (long)LIP * LT_, (long)K_ * LT_, 0, 0,
        wv_v, (long)LIP * K_, Whv, lv + (long)h * B_ * LI_, LI_);
    // wvvc[b][x][k] = aff[b] . wv_vT[b]^T ; fused lq[h,b,x] += tanh(wq_q+acc).Whq
    mfma_nt<EPI_TANH><<<4 * 4 * B_, blk, 0, stream>>>(
        aff, wv_vT, nullptr, nullptr, LIP, 4, 4,
        (long)LT_ * LIP, (long)K_ * LIP, 0, 0,
        wq_q, (long)LT_ * K_, Whq, lq + (long)h * B_ * LT_, LT_);
  }

  softmax_att<<<dim3(B_, H_), blk, 0, stream>>>(lv, lq, attvG, attqG);
  ctx_head<<<dim3(B_, D_ / 128), blk, 0, stream>>>(attvG, attqG, image, text, head);
  out_proj<<<D_, blk, 0, stream>>>(head, Wo, bo, out);
}

// Round 4
// 1036.150 us; speedup vs baseline: 6.7973x; 1.3170x over previous
//
#include <hip/hip_runtime.h>
#include <math.h>

#define B_  32
#define LT_ 512
#define LI_ 576
#define LIP 640           // image tokens padded to a multiple of 128
#define D_  768
#define H_  8
#define K_  512
#define NTOK  (LI_ + LT_) // 1088
#define CSPLIT 16
#define TPB   (NTOK / CSPLIT)  // 68 tokens per ctx block
#define NHEAD ((long)H_ * B_ * D_)

typedef __attribute__((ext_vector_type(4))) short short4v;
typedef __attribute__((ext_vector_type(8))) unsigned short ushort8;
typedef __attribute__((ext_vector_type(8))) _Float16 f16x8;
typedef __attribute__((ext_vector_type(4))) float f32x4;

__device__ __forceinline__ unsigned short f2h(float x) {
  _Float16 h = (_Float16)x;                       // RNE
  return __builtin_bit_cast(unsigned short, h);
}
__device__ __forceinline__ float h2f(unsigned short u) {
  return (float)__builtin_bit_cast(_Float16, u);
}
__device__ __forceinline__ float ftanh(float x) {
  float e = __expf(2.f * x);                      // saturates correctly at +-inf
  return 1.f - 2.f * __builtin_amdgcn_rcpf(e + 1.f);
}

__device__ __forceinline__ void gl_lds16(const void* g, void* l) {
  __builtin_amdgcn_global_load_lds(
      (const __attribute__((address_space(1))) void*)g,
      (__attribute__((address_space(3))) void*)l, 16, 0, 0);
}

// ---------------------------------------------------------------------------
// NT fp16 MFMA GEMM: C[m,n] = sum_k A[m*Kd+k]*B[n*Kd+k]
// 128x128 tile, BK=64, 4 waves (2x2 of 64x64), XCD-swizzled 1D grid (m204),
// LDS chunk^(row&7) XOR swizzle on both sides (G4 recipe, rule #21).
// EPI_PLAIN: store fp16 C.
// EPI_T:     store fp16 C and C^T (padded-LDS transpose, ld=136, LDS union).
// EPI_TANH:  out[row] += sum_col ftanh(h2f(base[row,col]) + acc) * wvec[col]
// ---------------------------------------------------------------------------
#define EPI_PLAIN 0
#define EPI_T     1
#define EPI_TANH  2

template<int EPI>
__global__ __launch_bounds__(256) void mfma_nt(
    const unsigned short* __restrict__ Ag, const unsigned short* __restrict__ Bg,
    unsigned short* __restrict__ Cg, unsigned short* __restrict__ CTg,
    int Kd, int gx, int gy,
    long sA, long sB, long sC, long sCT,
    const unsigned short* __restrict__ baseg, long sBase,
    const float* __restrict__ wvec, float* __restrict__ outv, int valid_rows)
{
  // --- bijective XCD-aware swizzle of the 1D grid (m204) ---
  const int orig = blockIdx.x, nwg = gridDim.x;
  const int q = nwg >> 3, r = nwg & 7;
  const int xcd = orig & 7, idx = orig >> 3;
  const int wg = (xcd < r ? xcd * (q + 1) : r * (q + 1) + (xcd - r) * q) + idx;
  const int bx = wg % gx, tmp = wg / gx, by = tmp % gy, bz = tmp / gy;

  __shared__ unsigned short LDSU[EPI == EPI_T ? 17408 : 16384];
  unsigned short* As = LDSU;          // 128 x 64
  unsigned short* Bs = LDSU + 8192;   // 128 x 64

  const int t = threadIdx.x;
  const int lane = t & 63, w = t >> 6;
  const int wr = w >> 1, wc = w & 1;
  const int m0 = bx * 128, n0 = by * 128;
  const int ldc = gy << 7;
  const unsigned short* A  = Ag + (long)bz * sA;
  const unsigned short* Bm = Bg + (long)bz * sB;

  // staging: issue i covers rows i*32 + w*8 + (lane>>3); chunk (lane&7),
  // global source chunk pre-swizzled: kc = (lane&7) ^ (row&7)
  const int srow = w * 8 + (lane >> 3);
  const unsigned short *aP0, *aP1, *aP2, *aP3, *bP0, *bP1, *bP2, *bP3;
  {
    int r0 = srow, r1 = srow + 32, r2 = srow + 64, r3 = srow + 96;
    int c0 = ((lane & 7) ^ (r0 & 7)) * 8, c1 = ((lane & 7) ^ (r1 & 7)) * 8;
    int c2 = ((lane & 7) ^ (r2 & 7)) * 8, c3 = ((lane & 7) ^ (r3 & 7)) * 8;
    aP0 = A + (long)(m0 + r0) * Kd + c0;  bP0 = Bm + (long)(n0 + r0) * Kd + c0;
    aP1 = A + (long)(m0 + r1) * Kd + c1;  bP1 = Bm + (long)(n0 + r1) * Kd + c1;
    aP2 = A + (long)(m0 + r2) * Kd + c2;  bP2 = Bm + (long)(n0 + r2) * Kd + c2;
    aP3 = A + (long)(m0 + r3) * Kd + c3;  bP3 = Bm + (long)(n0 + r3) * Kd + c3;
  }
  unsigned short* asb0 = As + (w * 8) * 64;
  unsigned short* asb1 = As + (32 + w * 8) * 64;
  unsigned short* asb2 = As + (64 + w * 8) * 64;
  unsigned short* asb3 = As + (96 + w * 8) * 64;
  unsigned short* bsb0 = Bs + (w * 8) * 64;
  unsigned short* bsb1 = Bs + (32 + w * 8) * 64;
  unsigned short* bsb2 = Bs + (64 + w * 8) * 64;
  unsigned short* bsb3 = Bs + (96 + w * 8) * 64;

  f32x4 acc[4][4];
  #pragma unroll
  for (int i = 0; i < 4; ++i)
    #pragma unroll
    for (int j = 0; j < 4; ++j)
      acc[i][j] = (f32x4){0.f, 0.f, 0.f, 0.f};

  const int rl = lane & 15, g = lane >> 4;
  const int aslot = (g ^ (rl & 7)) << 3;        // k-chunk for k 0..31
  const int aslot2 = aslot ^ 32;                // k-chunk for k 32..63

  for (int k0 = 0; k0 < Kd; k0 += 64) {
    __syncthreads();
    gl_lds16(aP0 + k0, asb0);  gl_lds16(bP0 + k0, bsb0);
    gl_lds16(aP1 + k0, asb1);  gl_lds16(bP1 + k0, bsb1);
    gl_lds16(aP2 + k0, asb2);  gl_lds16(bP2 + k0, bsb2);
    gl_lds16(aP3 + k0, asb3);  gl_lds16(bP3 + k0, bsb3);
    __syncthreads();
    f16x8 af[4], bf[4];
    #pragma unroll
    for (int i = 0; i < 4; ++i) {
      af[i] = *(const f16x8*)&As[(wr * 64 + i * 16 + rl) * 64 + aslot];
      bf[i] = *(const f16x8*)&Bs[(wc * 64 + i * 16 + rl) * 64 + aslot];
    }
    #pragma unroll
    for (int i = 0; i < 4; ++i)
      #pragma unroll
      for (int j = 0; j < 4; ++j)
        acc[i][j] = __builtin_amdgcn_mfma_f32_16x16x32_f16(af[i], bf[j], acc[i][j], 0, 0, 0);
    #pragma unroll
    for (int i = 0; i < 4; ++i) {
      af[i] = *(const f16x8*)&As[(wr * 64 + i * 16 + rl) * 64 + aslot2];
      bf[i] = *(const f16x8*)&Bs[(wc * 64 + i * 16 + rl) * 64 + aslot2];
    }
    #pragma unroll
    for (int i = 0; i < 4; ++i)
      #pragma unroll
      for (int j = 0; j < 4; ++j)
        acc[i][j] = __builtin_amdgcn_mfma_f32_16x16x32_f16(af[i], bf[j], acc[i][j], 0, 0, 0);
  }

  const int rg = lane >> 4;
  if (EPI != EPI_TANH) {
    unsigned short* C = Cg + (long)bz * sC;
    unsigned short* T = LDSU;                     // union: reuse staging LDS
    if (EPI == EPI_T) __syncthreads();            // all ds_reads of As/Bs done
    #pragma unroll
    for (int i = 0; i < 4; ++i)
      #pragma unroll
      for (int j = 0; j < 4; ++j) {
        unsigned short hv[4];
        #pragma unroll
        for (int rr = 0; rr < 4; ++rr) {
          int row = wr * 64 + i * 16 + rg * 4 + rr;      // m-local
          int col = wc * 64 + j * 16 + rl;               // n-local
          hv[rr] = f2h(acc[i][j][rr]);
          C[(long)(m0 + row) * ldc + n0 + col] = hv[rr];
        }
        if (EPI == EPI_T) {
          int col = wc * 64 + j * 16 + rl;
          int row0 = wr * 64 + i * 16 + rg * 4;
          *(short4v*)&T[col * 136 + row0] =
              (short4v){(short)hv[0], (short)hv[1], (short)hv[2], (short)hv[3]};
        }
      }
    if (EPI == EPI_T) {
      __syncthreads();
      unsigned short* CT = CTg + (long)bz * sCT;
      const int ldTm = gx << 7;
      #pragma unroll
      for (int rr = 0; rr < 8; ++rr) {
        int rn = rr * 16 + (t >> 4);      // n-local
        int c8 = (t & 15) * 8;            // m-local
        *(ushort8*)(CT + (long)(n0 + rn) * ldTm + m0 + c8) = *(const ushort8*)&T[rn * 136 + c8];
      }
    }
  } else {
    const unsigned short* base = baseg + (long)bz * sBase;
    float* outp = outv + (long)bz * valid_rows;
    #pragma unroll
    for (int i = 0; i < 4; ++i)
      #pragma unroll
      for (int rr = 0; rr < 4; ++rr) {
        int row = m0 + wr * 64 + i * 16 + rg * 4 + rr;
        float s = 0.f;
        #pragma unroll
        for (int j = 0; j < 4; ++j) {
          int col = n0 + wc * 64 + j * 16 + rl;
          float v = acc[i][rr < 0 ? 0 : j][rr] + h2f(base[(long)row * ldc + col]);
          s += ftanh(v) * wvec[col];
        }
        s += __shfl_xor(s, 1, 64);
        s += __shfl_xor(s, 2, 64);
        s += __shfl_xor(s, 4, 64);
        s += __shfl_xor(s, 8, 64);
        if (rl == 0 && row < valid_rows)
          atomicAdd(&outp[row], s);
      }
  }
}

// --------------------------- helper kernels --------------------------------
__global__ __launch_bounds__(256) void cast_f16(
    const float* __restrict__ in, unsigned short* __restrict__ out, long n8)
{
  long i = (long)blockIdx.x * 256 + threadIdx.x;
  if (i >= n8) return;
  float4 v0 = ((const float4*)in)[i * 2];
  float4 v1 = ((const float4*)in)[i * 2 + 1];
  ushort8 o;
  o[0] = f2h(v0.x); o[1] = f2h(v0.y); o[2] = f2h(v0.z); o[3] = f2h(v0.w);
  o[4] = f2h(v1.x); o[5] = f2h(v1.y); o[6] = f2h(v1.z); o[7] = f2h(v1.w);
  *(ushort8*)(out + i * 8) = o;
}

__global__ __launch_bounds__(256) void cast_pad_image(
    const float* __restrict__ in, unsigned short* __restrict__ out)
{
  long tid = (long)blockIdx.x * 256 + threadIdx.x;
  const long tot = (long)B_ * LIP * (D_ / 8);
  if (tid >= tot) return;
  int e8 = (int)(tid % (D_ / 8));
  long rw = tid / (D_ / 8);
  int y  = (int)(rw % LIP);
  long b = rw / LIP;
  ushort8 o;
  if (y < LI_) {
    const float* p = in + ((b * LI_ + y) * D_ + e8 * 8);
    float4 v0 = *(const float4*)p, v1 = *(const float4*)(p + 4);
    o[0] = f2h(v0.x); o[1] = f2h(v0.y); o[2] = f2h(v0.z); o[3] = f2h(v0.w);
    o[4] = f2h(v1.x); o[5] = f2h(v1.y); o[6] = f2h(v1.z); o[7] = f2h(v1.w);
  } else {
    #pragma unroll
    for (int j = 0; j < 8; ++j) o[j] = 0;
  }
  *(ushort8*)(out + rw * D_ + e8 * 8) = o;
}

__global__ __launch_bounds__(256) void zero_f32(float* __restrict__ p, long n) {
  long i = (long)blockIdx.x * 256 + threadIdx.x;
  if (i < n) p[i] = 0.f;
}

// per (b,h): softmax over LI (lv) and LT (lq) -> normalized att weights
__global__ __launch_bounds__(256) void softmax_att(
    const float* __restrict__ lv, const float* __restrict__ lq,
    float* __restrict__ attvG, float* __restrict__ attqG)
{
  const int b = blockIdx.x, h = blockIdx.y;
  const int t = threadIdx.x;
  __shared__ float buf[LI_];
  __shared__ float red[4];

  const float* lvp = lv + ((long)h * B_ + b) * LI_;
  float m = -1e30f;
  for (int i = t; i < LI_; i += 256) m = fmaxf(m, lvp[i]);
  #pragma unroll
  for (int o = 32; o > 0; o >>= 1) m = fmaxf(m, __shfl_down(m, o, 64));
  if ((t & 63) == 0) red[t >> 6] = m;
  __syncthreads();
  m = fmaxf(fmaxf(red[0], red[1]), fmaxf(red[2], red[3]));
  __syncthreads();
  float s = 0.f;
  for (int i = t; i < LI_; i += 256) { float e = __expf(lvp[i] - m); buf[i] = e; s += e; }
  #pragma unroll
  for (int o = 32; o > 0; o >>= 1) s += __shfl_down(s, o, 64);
  if ((t & 63) == 0) red[t >> 6] = s;
  __syncthreads();
  s = red[0] + red[1] + red[2] + red[3];
  {
    float inv = 1.f / s;
    float* op = attvG + ((long)h * B_ + b) * LI_;
    for (int i = t; i < LI_; i += 256) op[i] = buf[i] * inv;
  }
  __syncthreads();

  const float* lqp = lq + ((long)h * B_ + b) * LT_;
  m = -1e30f;
  for (int i = t; i < LT_; i += 256) m = fmaxf(m, lqp[i]);
  #pragma unroll
  for (int o = 32; o > 0; o >>= 1) m = fmaxf(m, __shfl_down(m, o, 64));
  if ((t & 63) == 0) red[t >> 6] = m;
  __syncthreads();
  m = fmaxf(fmaxf(red[0], red[1]), fmaxf(red[2], red[3]));
  __syncthreads();
  s = 0.f;
  for (int i = t; i < LT_; i += 256) { float e = __expf(lqp[i] - m); buf[i] = e; s += e; }
  #pragma unroll
  for (int o = 32; o > 0; o >>= 1) s += __shfl_down(s, o, 64);
  if ((t & 63) == 0) red[t >> 6] = s;
  __syncthreads();
  s = red[0] + red[1] + red[2] + red[3];
  {
    float inv = 1.f / s;
    float* op = attqG + ((long)h * B_ + b) * LT_;
    for (int i = t; i < LT_; i += 256) op[i] = buf[i] * inv;
  }
}

// partial context: grid (B, D/128, CSPLIT); 256 thr = 128 d-lanes x 2 groups.
// head_part[s][h,b,d] = sum over this slice's tokens of att*token (fp16 reads)
__global__ __launch_bounds__(256) void ctx_part(
    const float* __restrict__ attvG, const float* __restrict__ attqG,
    const unsigned short* __restrict__ text_h,   // base; image_p = text_h + N_TEXT
    float* __restrict__ head_part)
{
  const int b = blockIdx.x, d0 = blockIdx.y * 128, s = blockIdx.z;
  const int t = threadIdx.x, dl = t & 127, g = t >> 7;
  const long IMG_OFF = (long)B_ * LT_ * D_;      // image_p - text_h in ushorts
  __shared__ float wts[H_][TPB];
  __shared__ long  roff[TPB];
  __shared__ float red[H_][128];
  const int tok0 = s * TPB;
  for (int i = t; i < H_ * TPB; i += 256) {
    int h = i / TPB, j = i % TPB, tok = tok0 + j;
    wts[h][j] = tok < LI_ ? attvG[((long)h * B_ + b) * LI_ + tok]
                          : attqG[((long)h * B_ + b) * LT_ + (tok - LI_)];
  }
  if (t < TPB) {
    int tok = tok0 + t;
    roff[t] = tok < LI_ ? IMG_OFF + ((long)b * LIP + tok) * D_
                        : ((long)b * LT_ + (tok - LI_)) * D_;
  }
  __syncthreads();
  float acc[H_];
  #pragma unroll
  for (int h = 0; h < H_; ++h) acc[h] = 0.f;
  #pragma unroll 4
  for (int j = g; j < TPB; j += 2) {
    float val = h2f(text_h[roff[j] + d0 + dl]);
    #pragma unroll
    for (int h = 0; h < H_; ++h) acc[h] = fmaf(wts[h][j], val, acc[h]);
  }
  if (g == 1) {
    #pragma unroll
    for (int h = 0; h < H_; ++h) red[h][dl] = acc[h];
  }
  __syncthreads();
  if (g == 0) {
    float* hp = head_part + (long)s * NHEAD;
    #pragma unroll
    for (int h = 0; h < H_; ++h)
      hp[((long)h * B_ + b) * D_ + d0 + dl] = acc[h] + red[h][dl];
  }
}

__global__ __launch_bounds__(256) void reduce_head(
    const float* __restrict__ head_part, float* __restrict__ head)
{
  long i = (long)blockIdx.x * 256 + threadIdx.x;   // grid covers NHEAD exactly
  float s = 0.f;
  #pragma unroll
  for (int p = 0; p < CSPLIT; ++p) s += head_part[(long)p * NHEAD + i];
  head[i] = s;
}

// out[b,d] = bo[d] + sum_{h,e} head[h,b,e] * Wo[d, h*D+e]   (one block per d)
__global__ __launch_bounds__(256) void out_proj(
    const float* __restrict__ head, const float* __restrict__ Wo,
    const float* __restrict__ bo, float* __restrict__ out)
{
  const int d = blockIdx.x, t = threadIdx.x;
  float acc[B_];
  #pragma unroll
  for (int b = 0; b < B_; ++b) acc[b] = 0.f;
  const float4* wrow4 = (const float4*)(Wo + (long)d * (H_ * D_));
  for (int k4 = t; k4 < H_ * D_ / 4; k4 += 256) {
    float4 wv = wrow4[k4];
    int k = k4 * 4;
    int h = k / D_, e = k - h * D_;
    const float* hp = head + (long)h * B_ * D_ + e;
    #pragma unroll
    for (int b = 0; b < B_; ++b) {
      const float* p = hp + (long)b * D_;
      acc[b] += wv.x * p[0] + wv.y * p[1] + wv.z * p[2] + wv.w * p[3];
    }
  }
  __shared__ float red[4][B_];
  const int w4 = t >> 6;
  #pragma unroll
  for (int b = 0; b < B_; ++b) {
    float v = acc[b];
    #pragma unroll
    for (int o = 32; o > 0; o >>= 1) v += __shfl_down(v, o, 64);
    if ((t & 63) == 0) red[w4][b] = v;
  }
  __syncthreads();
  if (t < B_)
    out[(long)t * D_ + d] = red[0][t] + red[1][t] + red[2][t] + red[3][t] + bo[d];
}

// ---------------------------------------------------------------------------
extern "C" void kernel_launch(void* const* d_in, const int* in_sizes, int n_in,
                              void* d_out, int out_size, void* d_ws, size_t ws_size,
                              hipStream_t stream)
{
  const float* text  = (const float*)d_in[0];
  const float* image = (const float*)d_in[1];
  const float* Wb  = (const float*)d_in[3];
  const float* Wv  = (const float*)d_in[4];
  const float* Wq  = (const float*)d_in[5];
  const float* Whv = (const float*)d_in[6];
  const float* Whq = (const float*)d_in[7];
  const float* Wo  = (const float*)d_in[8];
  const float* bo  = (const float*)d_in[9];
  float* out = (float*)d_out;

  const long N_TEXT = (long)B_ * LT_ * D_;
  const long N_IMGP = (long)B_ * LIP * D_;
  const long N_WV   = (long)K_ * D_;
  const long N_WB   = (long)H_ * D_ * D_;
  const long N_WVV  = (long)B_ * LIP * K_;
  const long N_WQQ  = (long)B_ * LT_ * K_;
  const long N_PT   = (long)B_ * LT_ * D_;
  const long N_AFF  = (long)B_ * LT_ * LIP;
  const long N_LV   = (long)H_ * B_ * LI_;
  const long N_LQ   = (long)H_ * B_ * LT_;

  unsigned short* wsu = (unsigned short*)d_ws;
  long off = 0;
  unsigned short* text_h  = wsu + off; off += N_TEXT;
  unsigned short* image_p = wsu + off; off += N_IMGP;
  unsigned short* Wv_h    = wsu + off; off += N_WV;
  unsigned short* Wq_h    = wsu + off; off += N_WV;
  unsigned short* Wb_h    = wsu + off; off += N_WB;
  unsigned short* wv_v    = wsu + off; off += N_WVV;
  unsigned short* wq_q    = wsu + off; off += N_WQQ;
  unsigned short* wv_vT   = wsu + off; off += N_WVV;
  unsigned short* wq_qT   = wsu + off; off += N_WQQ;
  unsigned short* pt_h    = wsu + off; off += N_PT;
  unsigned short* aff     = wsu + off; off += N_AFF;
  unsigned short* affT    = wsu + off; off += N_AFF;
  float* lv        = (float*)(wsu + off);
  float* lq        = lv + N_LV;
  float* attvG     = lq + N_LQ;
  float* attqG     = attvG + N_LV;
  float* head      = attqG + N_LQ;
  float* head_part = head + NHEAD;
  const size_t need = (size_t)off * 2 +
      (size_t)(2 * (N_LV + N_LQ) + NHEAD + CSPLIT * NHEAD) * 4;
  if (ws_size < need) return;

  dim3 blk(256);

  cast_f16<<<(unsigned)(N_TEXT / 8 / 256), blk, 0, stream>>>(text, text_h, N_TEXT / 8);
  cast_pad_image<<<(unsigned)((B_ * LIP * (D_ / 8) + 255) / 256), blk, 0, stream>>>(image, image_p);
  cast_f16<<<(unsigned)(N_WV / 8 / 256), blk, 0, stream>>>(Wv, Wv_h, N_WV / 8);
  cast_f16<<<(unsigned)(N_WV / 8 / 256), blk, 0, stream>>>(Wq, Wq_h, N_WV / 8);
  cast_f16<<<(unsigned)(N_WB / 8 / 256), blk, 0, stream>>>(Wb, Wb_h, N_WB / 8);
  zero_f32<<<(unsigned)((N_LV + N_LQ + 255) / 256), blk, 0, stream>>>(lv, N_LV + N_LQ);

  // wv_v[b][y][k] = image_p[b] . Wv^T  (+ transpose wv_vT[b][k][y])
  mfma_nt<EPI_T><<<5 * 4 * B_, blk, 0, stream>>>(
      image_p, Wv_h, wv_v, wv_vT, D_, 5, 4,
      (long)LIP * D_, 0, (long)LIP * K_, (long)K_ * LIP,
      nullptr, 0, nullptr, nullptr, 0);
  // wq_q[b][x][k] = text[b] . Wq^T  (+ transpose)
  mfma_nt<EPI_T><<<4 * 4 * B_, blk, 0, stream>>>(
      text_h, Wq_h, wq_q, wq_qT, D_, 4, 4,
      (long)LT_ * D_, 0, (long)LT_ * K_, (long)K_ * LT_,
      nullptr, 0, nullptr, nullptr, 0);

  for (int h = 0; h < H_; ++h) {
    // pt[b*512+x, e] = text . Wb[h]^T
    mfma_nt<EPI_PLAIN><<<128 * 6, blk, 0, stream>>>(
        text_h, Wb_h + (long)h * D_ * D_, pt_h, nullptr, D_, 128, 6,
        0, 0, 0, 0, nullptr, 0, nullptr, nullptr, 0);
    // aff[b][x][y] = pt[b] . image_p[b]^T  (+ transpose affT[b][y][x])
    mfma_nt<EPI_T><<<4 * 5 * B_, blk, 0, stream>>>(
        pt_h, image_p, aff, affT, D_, 4, 5,
        (long)LT_ * D_, (long)LIP * D_, (long)LT_ * LIP, (long)LIP * LT_,
        nullptr, 0, nullptr, nullptr, 0);
    // wqqc[b][y][k] = affT[b] . wq_qT[b]^T ; fused lv[h,b,y] += tanh(wv_v+acc).Whv
    mfma_nt<EPI_TANH><<<5 * 4 * B_, blk, 0, stream>>>(
        affT, wq_qT, nullptr, nullptr, LT_, 5, 4,
        (long)LIP * LT_, (long)K_ * LT_, 0, 0,
        wv_v, (long)LIP * K_, Whv, lv + (long)h * B_ * LI_, LI_);
    // wvvc[b][x][k] = aff[b] . wv_vT[b]^T ; fused lq[h,b,x] += tanh(wq_q+acc).Whq
    mfma_nt<EPI_TANH><<<4 * 4 * B_, blk, 0, stream>>>(
        aff, wv_vT, nullptr, nullptr, LIP, 4, 4,
        (long)LT_ * LIP, (long)K_ * LIP, 0, 0,
        wq_q, (long)LT_ * K_, Whq, lq + (long)h * B_ * LT_, LT_);
  }

  softmax_att<<<dim3(B_, H_), blk, 0, stream>>>(lv, lq, attvG, attqG);
  ctx_part<<<dim3(B_, D_ / 128, CSPLIT), blk, 0, stream>>>(attvG, attqG, text_h, head_part);
  reduce_head<<<(unsigned)(NHEAD / 256), blk, 0, stream>>>(head_part, head);
  out_proj<<<D_, blk, 0, stream>>>(head, Wo, bo, out);
}